// Round 3
// baseline (255.817 us; speedup 1.0000x reference)
//
#include <hip/hip_runtime.h>

#define BB 32
#define TT 128
#define PP 512
#define DD 300
#define NPK 7168   // P*ND*MAXL = 512*2*7
#define KP 320     // K padded to multiple of 32
#define NT 112     // fused n-tile = 8 patterns * 14
#define NEG -1e30f

typedef _Float16 half8 __attribute__((ext_vector_type(8)));
typedef _Float16 half4 __attribute__((ext_vector_type(4)));
typedef float floatx4 __attribute__((ext_vector_type(4)));

__device__ __forceinline__ void async_load16(const void* g, void* l) {
    __builtin_amdgcn_global_load_lds(
        (const __attribute__((address_space(1))) void*)g,
        (__attribute__((address_space(3))) void*)l, 16, 0, 0);
}

__device__ __forceinline__ floatx4 mfma16(half8 a, half8 b, floatx4 c) {
    return __builtin_amdgcn_mfma_f32_16x16x32_f16(a, b, c, 0, 0, 0);
}

// ---------------------------------------------------------------------------
// Pack kernels: error-free f16 Dekker split. x = hi + lo*2^-12 (lo stored
// pre-scaled by 4096). Dropped term al*bl <= 2^-24|a||b| -> fp32-grade.
// ---------------------------------------------------------------------------
__global__ __launch_bounds__(256) void pack_a_kernel(
    const int* __restrict__ tokens, const float* __restrict__ emb,
    _Float16* __restrict__ Ah, _Float16* __restrict__ Al)
{
    const int idx = blockIdx.x * 256 + threadIdx.x;
    if (idx >= 4096 * 80) return;
    const int m = idx / 80;
    const int c = idx - m * 80;
    float4 x = make_float4(0.f, 0.f, 0.f, 0.f);
    if (c < 75) x = *(const float4*)(emb + (size_t)tokens[m] * DD + c * 4);
    half4 h, l;
    h.x = (_Float16)x.x; l.x = (_Float16)((x.x - (float)h.x) * 4096.f);
    h.y = (_Float16)x.y; l.y = (_Float16)((x.y - (float)h.y) * 4096.f);
    h.z = (_Float16)x.z; l.z = (_Float16)((x.z - (float)h.z) * 4096.f);
    h.w = (_Float16)x.w; l.w = (_Float16)((x.w - (float)h.w) * 4096.f);
    *(half4*)(Ah + (size_t)m * KP + c * 4) = h;
    *(half4*)(Al + (size_t)m * KP + c * 4) = l;
}

__global__ __launch_bounds__(256) void pack_b_kernel(
    const float* __restrict__ diags,
    _Float16* __restrict__ Bh, _Float16* __restrict__ Bl)
{
    const int idx = blockIdx.x * 256 + threadIdx.x;
    if (idx >= NPK * 80) return;
    const int n = idx / 80;
    const int c = idx - n * 80;
    float4 x = make_float4(0.f, 0.f, 0.f, 0.f);
    if (c < 75) x = *(const float4*)(diags + (size_t)n * DD + c * 4);
    half4 h, l;
    h.x = (_Float16)x.x; l.x = (_Float16)((x.x - (float)h.x) * 4096.f);
    h.y = (_Float16)x.y; l.y = (_Float16)((x.y - (float)h.y) * 4096.f);
    h.z = (_Float16)x.z; l.z = (_Float16)((x.z - (float)h.z) * 4096.f);
    h.w = (_Float16)x.w; l.w = (_Float16)((x.w - (float)h.w) * 4096.f);
    *(half4*)(Bh + (size_t)n * KP + c * 4) = h;
    *(half4*)(Bl + (size_t)n * KP + c * 4) = l;
}

// ---------------------------------------------------------------------------
// FUSED GEMM + SCAN. Block = one doc (blockIdx.y = b, m-rows b*128..b*128+127
// = all t) x 8 patterns (n0 = blockIdx.x*112). GEMM tile parked in LDS,
// then wave 0 runs the 128-step max-sum recurrence for 8 patterns on 8 lanes.
// ts never touches HBM.
// ---------------------------------------------------------------------------
__global__ __launch_bounds__(256, 2) void fused_kernel(
    const _Float16* __restrict__ Ah, const _Float16* __restrict__ Al,
    const _Float16* __restrict__ Bh, const _Float16* __restrict__ Bl,
    const float* __restrict__ bias,
    const float* __restrict__ epsilons,
    const int* __restrict__ doc_lens,
    float* __restrict__ scores)
{
    __shared__ __align__(16) union {
        struct {
            _Float16 AsH[128 * 32];   // 8 KB
            _Float16 AsL[128 * 32];   // 8 KB
            _Float16 BsH[NT * 32];    // 7 KB
            _Float16 BsL[NT * 32];    // 7 KB
        } st;
        float Ct[128][116];           // 59.4 KB (stride 116 breaks pow2)
    } sm;

    const int tid = threadIdx.x;
    const int w = tid >> 6, ln = tid & 63;
    const int b = blockIdx.y;
    const int n0 = blockIdx.x * NT;
    const int m0 = b * 128;

    floatx4 acc0[2][7], acc1[2][7];
    #pragma unroll
    for (int i = 0; i < 2; ++i)
        #pragma unroll
        for (int j = 0; j < 7; ++j) {
            acc0[i][j] = (floatx4){0.f, 0.f, 0.f, 0.f};
            acc1[i][j] = (floatx4){0.f, 0.f, 0.f, 0.f};
        }

    const int lrow = ln >> 2;   // staging: row within 16-row segment
    const int lkc  = ln & 3;    // staging: 16-byte chunk in 64-byte k-row
    const int fr   = ln & 15;   // fragment row index
    const int kg   = ln >> 4;   // k-group 0..3

    for (int kt = 0; kt < KP / 32; ++kt) {
        const int k0 = kt * 32;
        // staging: wave0->AsH(8 segs), wave1->AsL, wave2->BsH(7), wave3->BsL
        if (w == 0) {
            #pragma unroll
            for (int s = 0; s < 8; ++s)
                async_load16(Ah + (size_t)(m0 + s * 16 + lrow) * KP + k0 + lkc * 8,
                             &sm.st.AsH[s * 16 * 32]);
        } else if (w == 1) {
            #pragma unroll
            for (int s = 0; s < 8; ++s)
                async_load16(Al + (size_t)(m0 + s * 16 + lrow) * KP + k0 + lkc * 8,
                             &sm.st.AsL[s * 16 * 32]);
        } else if (w == 2) {
            #pragma unroll
            for (int s = 0; s < 7; ++s)
                async_load16(Bh + (size_t)(n0 + s * 16 + lrow) * KP + k0 + lkc * 8,
                             &sm.st.BsH[s * 16 * 32]);
        } else {
            #pragma unroll
            for (int s = 0; s < 7; ++s)
                async_load16(Bl + (size_t)(n0 + s * 16 + lrow) * KP + k0 + lkc * 8,
                             &sm.st.BsL[s * 16 * 32]);
        }
        __syncthreads();

        half8 ah[2], al[2];
        #pragma unroll
        for (int i = 0; i < 2; ++i) {
            const int off = (w * 32 + i * 16 + fr) * 32 + kg * 8;
            ah[i] = *(const half8*)&sm.st.AsH[off];
            al[i] = *(const half8*)&sm.st.AsL[off];
        }
        #pragma unroll
        for (int j = 0; j < 7; ++j) {
            const int off = (j * 16 + fr) * 32 + kg * 8;
            const half8 bh = *(const half8*)&sm.st.BsH[off];
            const half8 bl = *(const half8*)&sm.st.BsL[off];
            #pragma unroll
            for (int i = 0; i < 2; ++i) {
                acc0[i][j] = mfma16(ah[i], bh, acc0[i][j]);
                acc1[i][j] = mfma16(ah[i], bl, acc1[i][j]);
                acc1[i][j] = mfma16(al[i], bh, acc1[i][j]);
            }
        }
        __syncthreads();
    }

    // all waves done reading staging LDS -> safe to alias with Ct
    __syncthreads();

    // epilogue: C/D layout col=lane&15, row=(lane>>4)*4+reg
    #pragma unroll
    for (int j = 0; j < 7; ++j) {
        const int nl = j * 16 + fr;
        const float bj = bias[n0 + nl];
        #pragma unroll
        for (int i = 0; i < 2; ++i) {
            const int t0 = w * 32 + i * 16 + kg * 4;
            #pragma unroll
            for (int r = 0; r < 4; ++r)
                sm.Ct[t0 + r][nl] = acc0[i][j][r] + acc1[i][j][r] * (1.0f / 4096.0f) + bj;
        }
    }
    __syncthreads();

    // scan: wave 0, lane pl<8 handles pattern blockIdx.x*8+pl over t=0..127
    if (w == 0 && ln < 8) {
        const int p = n0 / 14 + ln;
        const int dl = doc_lens[b];
        float e0 = epsilons[p * 6 + 0], e1 = epsilons[p * 6 + 1];
        float e2 = epsilons[p * 6 + 2], e3 = epsilons[p * 6 + 3];
        float e4 = epsilons[p * 6 + 4], e5 = epsilons[p * 6 + 5];
        const bool end5 = (p < 256);

        float h0 = 0.f, h1 = NEG, h2 = NEG, h3 = NEG, h4 = NEG, h5 = NEG, h6 = NEG;
        float sc = NEG;
        const int co = ln * 14;

        float2 c0, c1, c2, c3, c4, c5, c6;     // current step's 14 values
        float2 d0, d1, d2, d3, d4, d5, d6;     // next step (prefetch)

        #define LOADROW(v0,v1,v2,v3,v4,v5,v6, t) do {            \
            const float2* _r = (const float2*)&sm.Ct[(t)][co];    \
            v0=_r[0]; v1=_r[1]; v2=_r[2]; v3=_r[3];               \
            v4=_r[4]; v5=_r[5]; v6=_r[6]; } while(0)

        #define STEP(v0,v1,v2,v3,v4,v5,v6, t) do {                                 \
            float ae0 = h0;                                                         \
            float ae1 = fmaxf(h1, h0 + e0);                                         \
            float ae2 = fmaxf(h2, h1 + e1);                                         \
            float ae3 = fmaxf(h3, h2 + e2);                                         \
            float ae4 = fmaxf(h4, h3 + e3);                                         \
            float ae5 = fmaxf(h5, h4 + e4);                                         \
            float ae6 = fmaxf(h6, h5 + e5);                                         \
            h0 = fmaxf(0.f,           ae0 + v0.x);                                  \
            h1 = fmaxf(ae0 + v3.y,    ae1 + v0.y);                                  \
            h2 = fmaxf(ae1 + v4.x,    ae2 + v1.x);                                  \
            h3 = fmaxf(ae2 + v4.y,    ae3 + v1.y);                                  \
            h4 = fmaxf(ae3 + v5.x,    ae4 + v2.x);                                  \
            h5 = fmaxf(ae4 + v5.y,    ae5 + v2.y);                                  \
            h6 = fmaxf(ae5 + v6.x,    ae6 + v3.x);                                  \
            const float endv = end5 ? h5 : h6;                                      \
            if ((t) < dl) sc = fmaxf(sc, endv); } while(0)

        LOADROW(c0,c1,c2,c3,c4,c5,c6, 0);
        for (int t = 0; t < TT - 2; t += 2) {
            LOADROW(d0,d1,d2,d3,d4,d5,d6, t + 1);
            STEP(c0,c1,c2,c3,c4,c5,c6, t);
            LOADROW(c0,c1,c2,c3,c4,c5,c6, t + 2);
            STEP(d0,d1,d2,d3,d4,d5,d6, t + 1);
        }
        LOADROW(d0,d1,d2,d3,d4,d5,d6, TT - 1);
        STEP(c0,c1,c2,c3,c4,c5,c6, TT - 2);
        STEP(d0,d1,d2,d3,d4,d5,d6, TT - 1);

        #undef LOADROW
        #undef STEP

        scores[p * BB + b] = sc;
    }
}

// ---------------------------------------------------------------------------
// Fallback fp32 GEMM + scan (only if ws_size too small for f16 pack buffers)
// ---------------------------------------------------------------------------
__global__ __launch_bounds__(256) void gemm_kernel(
    const int* __restrict__ tokens,
    const float* __restrict__ emb,
    const float* __restrict__ diags,
    const float* __restrict__ bias,
    float* __restrict__ C)
{
    __shared__ __align__(16) float As[16][132];
    __shared__ __align__(16) float Bs[16][132];
    __shared__ int rowbase[128];

    const int tid = threadIdx.x;
    const int n0 = blockIdx.x * 128;
    const int m0 = blockIdx.y * 128;

    if (tid < 128) rowbase[tid] = tokens[m0 + tid] * DD;
    __syncthreads();

    const int tx4 = (tid & 15) * 4;
    const int ty4 = (tid >> 4) * 4;
    const int r0  = tid >> 2;
    const int kq  = (tid & 3) * 4;

    float acc[8][8];
    #pragma unroll
    for (int i = 0; i < 8; ++i)
        #pragma unroll
        for (int j = 0; j < 8; ++j) acc[i][j] = 0.f;

    for (int kk = 0; kk < DD; kk += 16) {
        float4 a0, a1, b0, b1;
        const bool kval = (kk + kq) < DD;
        if (kval) {
            a0 = *(const float4*)(emb + rowbase[r0] + kk + kq);
            a1 = *(const float4*)(emb + rowbase[r0 + 64] + kk + kq);
            b0 = *(const float4*)(diags + (size_t)(n0 + r0) * DD + kk + kq);
            b1 = *(const float4*)(diags + (size_t)(n0 + r0 + 64) * DD + kk + kq);
        } else {
            a0 = make_float4(0.f, 0.f, 0.f, 0.f);
            a1 = a0; b0 = a0; b1 = a0;
        }
        __syncthreads();
        As[kq + 0][r0] = a0.x; As[kq + 1][r0] = a0.y; As[kq + 2][r0] = a0.z; As[kq + 3][r0] = a0.w;
        As[kq + 0][r0 + 64] = a1.x; As[kq + 1][r0 + 64] = a1.y; As[kq + 2][r0 + 64] = a1.z; As[kq + 3][r0 + 64] = a1.w;
        Bs[kq + 0][r0] = b0.x; Bs[kq + 1][r0] = b0.y; Bs[kq + 2][r0] = b0.z; Bs[kq + 3][r0] = b0.w;
        Bs[kq + 0][r0 + 64] = b1.x; Bs[kq + 1][r0 + 64] = b1.y; Bs[kq + 2][r0 + 64] = b1.z; Bs[kq + 3][r0 + 64] = b1.w;
        __syncthreads();
        #pragma unroll
        for (int k = 0; k < 16; ++k) {
            float4 av0 = *(const float4*)&As[k][ty4];
            float4 av1 = *(const float4*)&As[k][ty4 + 64];
            float4 bv0 = *(const float4*)&Bs[k][tx4];
            float4 bv1 = *(const float4*)&Bs[k][tx4 + 64];
            float a[8] = {av0.x, av0.y, av0.z, av0.w, av1.x, av1.y, av1.z, av1.w};
            float bb[8] = {bv0.x, bv0.y, bv0.z, bv0.w, bv1.x, bv1.y, bv1.z, bv1.w};
            #pragma unroll
            for (int i = 0; i < 8; ++i)
                #pragma unroll
                for (int j = 0; j < 8; ++j)
                    acc[i][j] = fmaf(a[i], bb[j], acc[i][j]);
        }
    }

    const float4 bias0 = *(const float4*)(bias + n0 + tx4);
    const float4 bias1 = *(const float4*)(bias + n0 + 64 + tx4);
    #pragma unroll
    for (int i = 0; i < 8; ++i) {
        const int m = m0 + ((i < 4) ? (ty4 + i) : (64 + ty4 + (i - 4)));
        float4 lo = make_float4(acc[i][0] + bias0.x, acc[i][1] + bias0.y,
                                acc[i][2] + bias0.z, acc[i][3] + bias0.w);
        float4 hi = make_float4(acc[i][4] + bias1.x, acc[i][5] + bias1.y,
                                acc[i][6] + bias1.z, acc[i][7] + bias1.w);
        *(float4*)(C + (size_t)m * NPK + n0 + tx4) = lo;
        *(float4*)(C + (size_t)m * NPK + n0 + 64 + tx4) = hi;
    }
}

__global__ __launch_bounds__(64) void scan_kernel(
    const float* __restrict__ ts,
    const float* __restrict__ epsilons,
    const int* __restrict__ doc_lens,
    float* __restrict__ scores)
{
    const int b = blockIdx.x;
    const int p = blockIdx.y * 64 + threadIdx.x;
    const int dl = doc_lens[b];

    float e[6];
    #pragma unroll
    for (int i = 0; i < 6; ++i) e[i] = epsilons[p * 6 + i];

    const float* base = ts + (size_t)b * TT * NPK + p * 14;

    float h0 = 0.f, h1 = NEG, h2 = NEG, h3 = NEG, h4 = NEG, h5 = NEG, h6 = NEG;
    float sc = NEG;
    const bool end5 = (p < 256);

    for (int t = 0; t < TT; ++t) {
        const float* tm = base + (size_t)t * NPK;
        float v[14];
        #pragma unroll
        for (int i = 0; i < 7; ++i) ((float2*)v)[i] = ((const float2*)tm)[i];
        float ae0 = h0;
        float ae1 = fmaxf(h1, h0 + e[0]);
        float ae2 = fmaxf(h2, h1 + e[1]);
        float ae3 = fmaxf(h3, h2 + e[2]);
        float ae4 = fmaxf(h4, h3 + e[3]);
        float ae5 = fmaxf(h5, h4 + e[4]);
        float ae6 = fmaxf(h6, h5 + e[5]);
        h0 = fmaxf(0.f,          ae0 + v[0]);
        h1 = fmaxf(ae0 + v[7],   ae1 + v[1]);
        h2 = fmaxf(ae1 + v[8],   ae2 + v[2]);
        h3 = fmaxf(ae2 + v[9],   ae3 + v[3]);
        h4 = fmaxf(ae3 + v[10],  ae4 + v[4]);
        h5 = fmaxf(ae4 + v[11],  ae5 + v[5]);
        h6 = fmaxf(ae5 + v[12],  ae6 + v[6]);
        const float endv = end5 ? h5 : h6;
        if (t < dl) sc = fmaxf(sc, endv);
    }
    scores[p * BB + b] = sc;
}

// ---------------------------------------------------------------------------
// Phase 3: BatchNorm (batch stats) + sign(relu) + final linear. One block.
// ---------------------------------------------------------------------------
__global__ __launch_bounds__(512) void finalize_kernel(
    const float* __restrict__ scores,
    const float* __restrict__ bn_w,
    const float* __restrict__ bn_b,
    const float* __restrict__ fw,
    const float* __restrict__ fb,
    float* __restrict__ out)
{
    __shared__ float acc[64];
    const int p = threadIdx.x;
    if (p < 64) acc[p] = 0.f;
    __syncthreads();

    float x[32];
    const float4* sp = (const float4*)(scores + p * 32);
    #pragma unroll
    for (int i = 0; i < 8; ++i) ((float4*)x)[i] = sp[i];

    float mean = 0.f;
    #pragma unroll
    for (int i = 0; i < 32; ++i) mean += x[i];
    mean *= (1.f / 32.f);
    float var = 0.f;
    #pragma unroll
    for (int i = 0; i < 32; ++i) { const float d = x[i] - mean; var = fmaf(d, d, var); }
    var *= (1.f / 32.f);

    const float scale = (1.f / sqrtf(var + 1e-5f)) * bn_w[p];
    const float shift = bn_b[p];
    const float w0 = fw[p], w1 = fw[PP + p];

    for (int b = 0; b < 32; ++b) {
        const float v = (x[b] - mean) * scale + shift;
        const bool bin = v > 0.f;
        float v0 = bin ? w0 : 0.f;
        float v1 = bin ? w1 : 0.f;
        #pragma unroll
        for (int o = 32; o; o >>= 1) {
            v0 += __shfl_xor(v0, o);
            v1 += __shfl_xor(v1, o);
        }
        if ((threadIdx.x & 63) == 0) {
            atomicAdd(&acc[b * 2 + 0], v0);
            atomicAdd(&acc[b * 2 + 1], v1);
        }
    }
    __syncthreads();
    if (p < 64) out[p] = acc[p] + fb[p & 1];
}

// ---------------------------------------------------------------------------
extern "C" void kernel_launch(void* const* d_in, const int* in_sizes, int n_in,
                              void* d_out, int out_size, void* d_ws, size_t ws_size,
                              hipStream_t stream) {
    const int*   tokens   = (const int*)d_in[0];
    const int*   doc_lens = (const int*)d_in[1];
    const float* emb      = (const float*)d_in[2];
    const float* diags    = (const float*)d_in[3];
    const float* bias     = (const float*)d_in[4];
    const float* eps      = (const float*)d_in[5];
    const float* bnw      = (const float*)d_in[6];
    const float* bnb      = (const float*)d_in[7];
    const float* fw       = (const float*)d_in[8];
    const float* fb       = (const float*)d_in[9];
    float* out = (float*)d_out;

    float* ts     = (float*)d_ws;                    // [4096][7168] (fallback only)
    float* scores = ts + (size_t)4096 * NPK;         // [512][32]
    _Float16* Ah  = (_Float16*)(scores + PP * BB);   // [4096][320] f16 hi
    _Float16* Al  = Ah + (size_t)4096 * KP;          // [4096][320] f16 lo*4096
    _Float16* Bh  = Al + (size_t)4096 * KP;          // [7168][320]
    _Float16* Bl  = Bh + (size_t)NPK * KP;
    const size_t needed = (size_t)((char*)(Bl + (size_t)NPK * KP) - (char*)d_ws);

    if (ws_size >= needed) {
        pack_a_kernel<<<1280, 256, 0, stream>>>(tokens, emb, Ah, Al);
        pack_b_kernel<<<2240, 256, 0, stream>>>(diags, Bh, Bl);
        fused_kernel<<<dim3(64, 32), 256, 0, stream>>>(Ah, Al, Bh, Bl, bias, eps,
                                                       doc_lens, scores);
    } else {
        gemm_kernel<<<dim3(56, 32), 256, 0, stream>>>(tokens, emb, diags, bias, ts);
        scan_kernel<<<dim3(32, 8), 64, 0, stream>>>(ts, eps, doc_lens, scores);
    }
    finalize_kernel<<<1, 512, 0, stream>>>(scores, bnw, bnb, fw, fb, out);
}

// Round 4
// 214.314 us; speedup vs baseline: 1.1937x; 1.1937x over previous
//
#include <hip/hip_runtime.h>

#define BB 32
#define TT 128
#define PP 512
#define DD 300
#define KP 320     // K padded: 300 data + slot 300 = bias + zeros
#define NR 13      // retained cols per pattern (tm[13] is dead)
#define NN 6656    // P * NR
#define NEG -1e30f

typedef _Float16 half8 __attribute__((ext_vector_type(8)));
typedef _Float16 half4 __attribute__((ext_vector_type(4)));
typedef float floatx4 __attribute__((ext_vector_type(4)));

__device__ __forceinline__ void async_load16(const void* g, void* l) {
    __builtin_amdgcn_global_load_lds(
        (const __attribute__((address_space(1))) void*)g,
        (__attribute__((address_space(3))) void*)l, 16, 0, 0);
}

__device__ __forceinline__ floatx4 mfma16(half8 a, half8 b, floatx4 c) {
    return __builtin_amdgcn_mfma_f32_16x16x32_f16(a, b, c, 0, 0, 0);
}

// ---------------------------------------------------------------------------
// Unified pack: error-free f16 Dekker split (x = hi + lo*2^-12, lo stored
// *4096). Rows 0..4095: A = emb[tokens[m]]; rows 4096..: B = diags row
// p*14+rr (rr<13, dropping the dead nd1/l6 column). K-slot 300 carries the
// bias: A gets 1.0, B gets (bias_hi, bias_lo*4096). Slots 301..319 zero.
// ---------------------------------------------------------------------------
__global__ __launch_bounds__(256) void pack_kernel(
    const int* __restrict__ tokens, const float* __restrict__ emb,
    const float* __restrict__ diags, const float* __restrict__ bias,
    _Float16* __restrict__ Ah, _Float16* __restrict__ Al,
    _Float16* __restrict__ Bh, _Float16* __restrict__ Bl)
{
    const int idx = blockIdx.x * 256 + threadIdx.x;
    if (idx >= (4096 + NN) * 80) return;
    const int r = idx / 80;
    const int c = idx - r * 80;

    float4 x = make_float4(0.f, 0.f, 0.f, 0.f);
    float4 xl_extra = make_float4(0.f, 0.f, 0.f, 0.f);  // lo override (bias slot)
    _Float16* dh;
    _Float16* dl;

    if (r < 4096) {
        if (c < 75) x = *(const float4*)(emb + (size_t)tokens[r] * DD + c * 4);
        else if (c == 75) x.x = 1.0f;   // bias multiplier
        dh = Ah + (size_t)r * KP + c * 4;
        dl = Al + (size_t)r * KP + c * 4;
    } else {
        const int n = r - 4096;
        const int p = n / NR;
        const int rr = n - p * NR;
        const int srow = p * 14 + rr;
        if (c < 75) x = *(const float4*)(diags + (size_t)srow * DD + c * 4);
        else if (c == 75) x.x = bias[srow];
        dh = Bh + (size_t)n * KP + c * 4;
        dl = Bl + (size_t)n * KP + c * 4;
    }

    half4 h, l;
    h.x = (_Float16)x.x; l.x = (_Float16)((x.x - (float)h.x) * 4096.f);
    h.y = (_Float16)x.y; l.y = (_Float16)((x.y - (float)h.y) * 4096.f);
    h.z = (_Float16)x.z; l.z = (_Float16)((x.z - (float)h.z) * 4096.f);
    h.w = (_Float16)x.w; l.w = (_Float16)((x.w - (float)h.w) * 4096.f);
    if (r < 4096 && c == 75) { l.x = (_Float16)0.f; }  // A bias slot: exact 1.0
    (void)xl_extra;
    *(half4*)dh = h;
    *(half4*)dl = l;
}

// ---------------------------------------------------------------------------
// GEMM: ts[m][n] = sum_k A[m][k]*B[n][k] (bias folded into k=300).
// 128x128 tile, BK=64 staged as 2x BK=32 sub-buffers (keeps 64B LDS row
// stride -> only free 2-way conflicts), 5 K-iters -> half the barrier drains.
// 3-product f16 Dekker split accumulated in acc0 (hh) and acc1 (hl+lh).
// ---------------------------------------------------------------------------
__global__ __launch_bounds__(256, 2) void gemm_kernel(
    const _Float16* __restrict__ Ah, const _Float16* __restrict__ Al,
    const _Float16* __restrict__ Bh, const _Float16* __restrict__ Bl,
    float* __restrict__ C)
{
    __shared__ __align__(16) _Float16 AsH[2][128 * 32];
    __shared__ __align__(16) _Float16 AsL[2][128 * 32];
    __shared__ __align__(16) _Float16 BsH[2][128 * 32];
    __shared__ __align__(16) _Float16 BsL[2][128 * 32];

    const int tid = threadIdx.x;
    const int w = tid >> 6, ln = tid & 63;
    const int n0 = blockIdx.x * 128, m0 = blockIdx.y * 128;
    const int wm = w & 1, wn = w >> 1;

    floatx4 acc0[4][4], acc1[4][4];
    #pragma unroll
    for (int i = 0; i < 4; ++i)
        #pragma unroll
        for (int j = 0; j < 4; ++j) {
            acc0[i][j] = (floatx4){0.f, 0.f, 0.f, 0.f};
            acc1[i][j] = (floatx4){0.f, 0.f, 0.f, 0.f};
        }

    // staging lane mapping: 64 lanes x 16B = 1024B = 16 rows of 64B
    const int srow = ln >> 2;       // row within 16-row segment
    const int sch  = (ln & 3) * 8;  // halves offset within 32-half row
    // fragment lane mapping
    const int fr = ln & 15;
    const int kg = ln >> 4;

    // each wave stages one array (A-hi / A-lo / B-hi / B-lo)
    const _Float16* gsrc = (w == 0) ? Ah + (size_t)m0 * KP
                        : (w == 1) ? Al + (size_t)m0 * KP
                        : (w == 2) ? Bh + (size_t)n0 * KP
                                   : Bl + (size_t)n0 * KP;
    _Float16* lbase = (w == 0) ? &AsH[0][0]
                    : (w == 1) ? &AsL[0][0]
                    : (w == 2) ? &BsH[0][0]
                               : &BsL[0][0];

    for (int kt = 0; kt < KP / 64; ++kt) {
        const int k0 = kt * 64;
        #pragma unroll
        for (int kb = 0; kb < 2; ++kb) {
            #pragma unroll
            for (int s = 0; s < 8; ++s) {
                async_load16(gsrc + (size_t)(s * 16 + srow) * KP + k0 + kb * 32 + sch,
                             lbase + kb * (128 * 32) + s * 16 * 32);
            }
        }
        __syncthreads();

        #pragma unroll
        for (int kb = 0; kb < 2; ++kb) {
            half8 ah4[4], al4[4];
            #pragma unroll
            for (int i = 0; i < 4; ++i) {
                const int off = (wm * 64 + i * 16 + fr) * 32 + kg * 8;
                ah4[i] = *(const half8*)&AsH[kb][off];
                al4[i] = *(const half8*)&AsL[kb][off];
            }
            #pragma unroll
            for (int j = 0; j < 4; ++j) {
                const int off = (wn * 64 + j * 16 + fr) * 32 + kg * 8;
                const half8 bh = *(const half8*)&BsH[kb][off];
                const half8 bl = *(const half8*)&BsL[kb][off];
                #pragma unroll
                for (int i = 0; i < 4; ++i) {
                    acc0[i][j] = mfma16(ah4[i], bh, acc0[i][j]);
                    acc1[i][j] = mfma16(ah4[i], bl, acc1[i][j]);
                    acc1[i][j] = mfma16(al4[i], bh, acc1[i][j]);
                }
            }
        }
        __syncthreads();
    }

    // epilogue: C/D layout col(n)=lane&15, row(m)=(lane>>4)*4+reg
    #pragma unroll
    for (int j = 0; j < 4; ++j) {
        const int n = n0 + wn * 64 + j * 16 + fr;
        #pragma unroll
        for (int i = 0; i < 4; ++i) {
            const int mb = m0 + wm * 64 + i * 16 + kg * 4;
            #pragma unroll
            for (int r = 0; r < 4; ++r)
                C[(size_t)(mb + r) * NN + n] =
                    acc0[i][j][r] + acc1[i][j][r] * (1.0f / 4096.0f);
        }
    }
}

// ---------------------------------------------------------------------------
// Max-sum scan: one thread per (b,p). 13 floats/step, depth-2 prefetch.
// v[0..6]=self-loop (diag0 l0..6), v[7..12]=main (diag1 l0..5).
// ---------------------------------------------------------------------------
__global__ __launch_bounds__(64) void scan_kernel(
    const float* __restrict__ ts,
    const float* __restrict__ epsilons,
    const int* __restrict__ doc_lens,
    float* __restrict__ scores)
{
    const int b = blockIdx.x;
    const int p = blockIdx.y * 64 + threadIdx.x;
    const int dl = doc_lens[b];

    float e[6];
    #pragma unroll
    for (int i = 0; i < 6; ++i) e[i] = epsilons[p * 6 + i];

    const float* base = ts + (size_t)b * TT * NN + p * NR;

    float h0 = 0.f, h1 = NEG, h2 = NEG, h3 = NEG, h4 = NEG, h5 = NEG, h6 = NEG;
    float sc = NEG;
    const bool end5 = (p < 256);

    float v0[NR], v1[NR];

    auto load = [&](float* v, int t) {
        const float* s = base + (size_t)t * NN;
        #pragma unroll
        for (int i = 0; i < NR; ++i) v[i] = s[i];
    };
    auto step = [&](const float* v, int t) {
        float ae0 = h0;
        float ae1 = fmaxf(h1, h0 + e[0]);
        float ae2 = fmaxf(h2, h1 + e[1]);
        float ae3 = fmaxf(h3, h2 + e[2]);
        float ae4 = fmaxf(h4, h3 + e[3]);
        float ae5 = fmaxf(h5, h4 + e[4]);
        float ae6 = fmaxf(h6, h5 + e[5]);
        h0 = fmaxf(0.f,          ae0 + v[0]);
        h1 = fmaxf(ae0 + v[7],   ae1 + v[1]);
        h2 = fmaxf(ae1 + v[8],   ae2 + v[2]);
        h3 = fmaxf(ae2 + v[9],   ae3 + v[3]);
        h4 = fmaxf(ae3 + v[10],  ae4 + v[4]);
        h5 = fmaxf(ae4 + v[11],  ae5 + v[5]);
        h6 = fmaxf(ae5 + v[12],  ae6 + v[6]);
        const float endv = end5 ? h5 : h6;
        if (t < dl) sc = fmaxf(sc, endv);
    };

    load(v0, 0);
    for (int t = 0; t < TT - 2; t += 2) {
        load(v1, t + 1);
        step(v0, t);
        load(v0, t + 2);
        step(v1, t + 1);
    }
    load(v1, TT - 1);
    step(v0, TT - 2);
    step(v1, TT - 1);

    scores[p * BB + b] = sc;
}

// ---------------------------------------------------------------------------
// BatchNorm (batch stats) + sign(relu) + final linear. One block.
// ---------------------------------------------------------------------------
__global__ __launch_bounds__(512) void finalize_kernel(
    const float* __restrict__ scores,
    const float* __restrict__ bn_w,
    const float* __restrict__ bn_b,
    const float* __restrict__ fw,
    const float* __restrict__ fb,
    float* __restrict__ out)
{
    __shared__ float acc[64];
    const int p = threadIdx.x;
    if (p < 64) acc[p] = 0.f;
    __syncthreads();

    float x[32];
    const float4* sp = (const float4*)(scores + p * 32);
    #pragma unroll
    for (int i = 0; i < 8; ++i) ((float4*)x)[i] = sp[i];

    float mean = 0.f;
    #pragma unroll
    for (int i = 0; i < 32; ++i) mean += x[i];
    mean *= (1.f / 32.f);
    float var = 0.f;
    #pragma unroll
    for (int i = 0; i < 32; ++i) { const float d = x[i] - mean; var = fmaf(d, d, var); }
    var *= (1.f / 32.f);

    const float scale = (1.f / sqrtf(var + 1e-5f)) * bn_w[p];
    const float shift = bn_b[p];
    const float w0 = fw[p], w1 = fw[PP + p];

    for (int b = 0; b < 32; ++b) {
        const float v = (x[b] - mean) * scale + shift;
        const bool bin = v > 0.f;
        float v0 = bin ? w0 : 0.f;
        float v1 = bin ? w1 : 0.f;
        #pragma unroll
        for (int o = 32; o; o >>= 1) {
            v0 += __shfl_xor(v0, o);
            v1 += __shfl_xor(v1, o);
        }
        if ((threadIdx.x & 63) == 0) {
            atomicAdd(&acc[b * 2 + 0], v0);
            atomicAdd(&acc[b * 2 + 1], v1);
        }
    }
    __syncthreads();
    if (p < 64) out[p] = acc[p] + fb[p & 1];
}

// ---------------------------------------------------------------------------
extern "C" void kernel_launch(void* const* d_in, const int* in_sizes, int n_in,
                              void* d_out, int out_size, void* d_ws, size_t ws_size,
                              hipStream_t stream) {
    const int*   tokens   = (const int*)d_in[0];
    const int*   doc_lens = (const int*)d_in[1];
    const float* emb      = (const float*)d_in[2];
    const float* diags    = (const float*)d_in[3];
    const float* bias     = (const float*)d_in[4];
    const float* eps      = (const float*)d_in[5];
    const float* bnw      = (const float*)d_in[6];
    const float* bnb      = (const float*)d_in[7];
    const float* fw       = (const float*)d_in[8];
    const float* fb       = (const float*)d_in[9];
    float* out = (float*)d_out;

    float* ts     = (float*)d_ws;                    // [4096][6656] = 109 MB
    float* scores = ts + (size_t)4096 * NN;          // [512][32]
    _Float16* Ah  = (_Float16*)(scores + PP * BB);   // [4096][320]
    _Float16* Al  = Ah + (size_t)4096 * KP;
    _Float16* Bh  = Al + (size_t)4096 * KP;          // [6656][320]
    _Float16* Bl  = Bh + (size_t)NN * KP;

    pack_kernel<<<((4096 + NN) * 80 + 255) / 256, 256, 0, stream>>>(
        tokens, emb, diags, bias, Ah, Al, Bh, Bl);
    gemm_kernel<<<dim3(NN / 128, 32), 256, 0, stream>>>(Ah, Al, Bh, Bl, ts);
    scan_kernel<<<dim3(32, 8), 64, 0, stream>>>(ts, eps, doc_lens, scores);
    finalize_kernel<<<1, 512, 0, stream>>>(scores, bnw, bnb, fw, fb, out);
}